// Round 18
// baseline (35.867 us; speedup 1.0000x reference)
//
#include <hip/hip_runtime.h>
#include <stdint.h>

// shape (1,1,192,224,192) f32
#define DD 192
#define HH 224
#define WW 192
#define PLANE (HH*WW)          // 43008
#define TOTAL (DD*HH*WW)       // 8257536

#define HT 8                   // output rows per block (4 waves x 2 rows)
#define TROWS 10               // HT+2 halo rows staged
#define DSEG 4                 // d-outputs per block
#define NSEG (DD/DSEG)         // 48
#define HTILES (HH/HT)         // 28 (exact)
#define NT 256                 // 4 waves; lane = 3 w-positions (64*3 = 192)
#define NBLOCKS (HTILES*NSEG)  // 1344 -> 5.25 blocks/CU, at the 5-block LDS cap

#define TILEF (TROWS*WW)       // 1920 floats per input per plane-tile
#define BUFF (2*TILEF)         // 3840 floats per buffer (I then J)
#define NPIECE 960             // 16B pieces per plane-pair (20 rows x 48)
#define GUARD 4                // head guard so lane0's [3l-1] read is in-bounds

typedef __attribute__((address_space(3))) uint32_t lds_t;
typedef __attribute__((address_space(1))) const uint32_t glb_t;

// Raw barrier + counted vmcnt. UNIFORM ledger: every wave issues exactly 4
// width-16 loads per stage (pieces t+m*256; p>=960 wraps to p-960 -- benign
// same-data duplicate writes, proven R16), so WAITV4 retires exactly the
// oldest stage. WIDTH-16 ONLY: width-12 global_load_lds corrupts on gfx950.
#define BARRIER() asm volatile("s_barrier" ::: "memory")
#define WAITV4()  asm volatile("s_waitcnt vmcnt(4)" ::: "memory")
#define WAITV0()  asm volatile("s_waitcnt vmcnt(0)" ::: "memory")

// Per-plane aggregates for 6 voxels: 2 output rows x 3 w; index = row*3 + j.
struct PP {
    float IPT[6], IPS[6], IHD[6];
    float JPT[6], JPS[6], JHD[6];
};

__global__ __launch_bounds__(NT) void ngf_main_kernel(
    const float* __restrict__ I, const float* __restrict__ J,
    float* __restrict__ partial)
{
    // All combine reads are b32 at (3*lane + c): 3 coprime 32 -> 2 lanes/bank
    // = conflict-free (rows are wave-uniform; row stride 192 = 0 mod 32).
    __shared__ __align__(16) float lds[GUARD + 2 * BUFF + 4];
    const float EPS2 = 0.04f;  // (2*0.1)^2 — 0.5 Sobel factor folded out

    int t    = threadIdx.x;
    int lane = t & 63;
    int w    = t >> 6;          // wave 0..3: owns output rows 2w, 2w+1
    int bid  = blockIdx.x;
    int th   = bid % HTILES;
    int seg  = bid / HTILES;
    int ds   = seg * DSEG;
    int hb   = th * HT;

    // --- staging: 960 float4 pieces, piece-contiguous LDS layout.
    //     piece p = inp*480 + r*48 + c  ->  LDS float offset 4p
    //     == inp*TILEF + r*WW + 4c (row-major), so combine addressing holds.
    const float* sp[4];
    int lo[4];
    #pragma unroll
    for (int m = 0; m < 4; ++m) {
        int p = t + m * NT;
        if (p >= NPIECE) p -= NPIECE;      // wrap: benign duplicate of pieces 0..63
        int inp = (p >= NPIECE / 2) ? 1 : 0;
        int q   = p - inp * (NPIECE / 2);
        int r   = q / 48, c = q % 48;
        int srow = min(max(hb - 1 + r, 0), HH - 1);   // replicate h-halo at load
        sp[m] = (inp ? J : I) + srow * WW + c * 4;
        lo[m] = GUARD + 4 * p;
    }

    auto stage = [&](int dp, int buf) {
        size_t poff = (size_t)dp * PLANE;
        #pragma unroll
        for (int m = 0; m < 4; ++m) {
            __builtin_amdgcn_global_load_lds((glb_t*)(sp[m] + poff),
                (lds_t*)(&lds[buf * BUFF + lo[m]]), 16, 0, 0);
        }
    };

    // --- compute mapping: lane covers w-positions 3*lane .. 3*lane+2 ---
    int l3 = 3 * lane;
    bool b0  = (lane == 0);    // true image left boundary
    bool b63 = (lane == 63);   // true image right boundary

    // Sliding 2-window combine: stream 4 staged rows (2w..2w+3); each row's
    // 3-wide sums / diffs are computed ONCE and accumulated into both
    // output-row windows (out0: b=0..2, out1: b=1..3).
    auto combine = [&](int buf) -> PP {
        PP P;
        #pragma unroll
        for (int j = 0; j < 6; ++j) {
            P.IPT[j] = 0.f; P.IPS[j] = 0.f; P.IHD[j] = 0.f;
            P.JPT[j] = 0.f; P.JPS[j] = 0.f; P.JHD[j] = 0.f;
        }
        const float* base = &lds[GUARD + buf * BUFF];
        #pragma unroll
        for (int b = 0; b < 4; ++b) {
            const float* BI = base + (2 * w + b) * WW;   // wave-uniform row
            const float* BJ = BI + TILEF;
            {
                float Lr = BI[l3 - 1];
                float x0 = BI[l3], x1 = BI[l3 + 1], x2 = BI[l3 + 2];
                float Rr = BI[l3 + 3];
                float L = b0  ? x0 : Lr;   // replicate pad at w=0
                float R = b63 ? x2 : Rr;   // replicate pad at w=191
                float s0 = L  + x0 + x1;
                float s1 = x0 + x1 + x2;
                float s2 = x1 + x2 + R;
                float t0 = x1 - L;
                float t1 = x2 - x0;
                float t2 = R  - x1;
                if (b <= 2) {
                    P.IPT[0] += t0; P.IPT[1] += t1; P.IPT[2] += t2;
                    P.IPS[0] += s0; P.IPS[1] += s1; P.IPS[2] += s2;
                    if (b == 0) { P.IHD[0] -= s0; P.IHD[1] -= s1; P.IHD[2] -= s2; }
                    if (b == 2) { P.IHD[0] += s0; P.IHD[1] += s1; P.IHD[2] += s2; }
                }
                if (b >= 1) {
                    P.IPT[3] += t0; P.IPT[4] += t1; P.IPT[5] += t2;
                    P.IPS[3] += s0; P.IPS[4] += s1; P.IPS[5] += s2;
                    if (b == 1) { P.IHD[3] -= s0; P.IHD[4] -= s1; P.IHD[5] -= s2; }
                    if (b == 3) { P.IHD[3] += s0; P.IHD[4] += s1; P.IHD[5] += s2; }
                }
            }
            {
                float Lr = BJ[l3 - 1];
                float x0 = BJ[l3], x1 = BJ[l3 + 1], x2 = BJ[l3 + 2];
                float Rr = BJ[l3 + 3];
                float L = b0  ? x0 : Lr;
                float R = b63 ? x2 : Rr;
                float s0 = L  + x0 + x1;
                float s1 = x0 + x1 + x2;
                float s2 = x1 + x2 + R;
                float t0 = x1 - L;
                float t1 = x2 - x0;
                float t2 = R  - x1;
                if (b <= 2) {
                    P.JPT[0] += t0; P.JPT[1] += t1; P.JPT[2] += t2;
                    P.JPS[0] += s0; P.JPS[1] += s1; P.JPS[2] += s2;
                    if (b == 0) { P.JHD[0] -= s0; P.JHD[1] -= s1; P.JHD[2] -= s2; }
                    if (b == 2) { P.JHD[0] += s0; P.JHD[1] += s1; P.JHD[2] += s2; }
                }
                if (b >= 1) {
                    P.JPT[3] += t0; P.JPT[4] += t1; P.JPT[5] += t2;
                    P.JPS[3] += s0; P.JPS[4] += s1; P.JPS[5] += s2;
                    if (b == 1) { P.JHD[3] -= s0; P.JHD[4] -= s1; P.JHD[5] -= s2; }
                    if (b == 3) { P.JHD[3] += s0; P.JHD[4] += s1; P.JHD[5] += s2; }
                }
            }
        }
        return P;
    };

    auto dcl = [&](int m) { return min(max(ds + m, 0), DD - 1); };

    // --- prologue ---
    // plane m -> buffer (m+1)&1 :  -1->0, 0->1, 1->0, 2->1
    PP p[3];
    stage(dcl(-1), 0);           // outstanding: {S-1}
    stage(dcl(0), 1);            // {S-1, S0}
    WAITV4(); BARRIER();         // plane -1 landed everywhere
    p[0] = combine(0);
    BARRIER();                   // all waves done reading buf0
    stage(dcl(1), 0);            // {S0, S1}
    WAITV4(); BARRIER();         // plane 0 landed
    p[1] = combine(1);
    BARRIER();                   // done reading buf1
    stage(dcl(2), 1);            // {S1, S2}

    float acc = 0.0f;
    #pragma unroll
    for (int k = 0; k < DSEG; ++k) {
        int buf = k & 1;                 // plane k+1 sits in buffer (k+2)&1 = k&1
        if (k < DSEG - 1) { WAITV4(); }  // retire S(k+1), keep S(k+2) in flight
        else             { WAITV0(); }   // last: drain
        BARRIER();                       // plane k+1 visible to all waves
        int sa = k % 3, sb2 = (k + 1) % 3, sc = (k + 2) % 3;
        p[sc] = combine(buf);

        #pragma unroll
        for (int j = 0; j < 6; ++j) {
            float Ix = p[sa].IPT[j] + p[sb2].IPT[j] + p[sc].IPT[j];
            float Iy = p[sa].IHD[j] + p[sb2].IHD[j] + p[sc].IHD[j];
            float Iz = p[sc].IPS[j] - p[sa].IPS[j];
            float Jx = p[sa].JPT[j] + p[sb2].JPT[j] + p[sc].JPT[j];
            float Jy = p[sa].JHD[j] + p[sb2].JHD[j] + p[sc].JHD[j];
            float Jz = p[sc].JPS[j] - p[sa].JPS[j];

            float Imag = fmaf(Ix, Ix, fmaf(Iy, Iy, fmaf(Iz, Iz, EPS2)));
            float Jmag = fmaf(Jx, Jx, fmaf(Jy, Jy, fmaf(Jz, Jz, EPS2)));
            float dot  = fmaf(Ix, Jx, fmaf(Iy, Jy, Iz * Jz));
            acc += 1.0f - (dot * dot) * __builtin_amdgcn_rcpf(Imag * Jmag);
        }

        if (k < DSEG - 1) {
            BARRIER();                   // all waves done reading buf
            if (k <= DSEG - 3)
                stage(dcl(k + 3), buf);  // plane k+3 -> buffer (k+4)&1 = k&1 ✓
        }
    }

    // --- reduction: 4 waves ---
    #pragma unroll
    for (int o = 32; o > 0; o >>= 1)
        acc += __shfl_down(acc, o, 64);

    __shared__ float smem[NT / 64];
    if (lane == 0) smem[w] = acc;
    __syncthreads();
    if (t == 0)
        partial[bid] = smem[0] + smem[1] + smem[2] + smem[3];
}

__global__ __launch_bounds__(256) void ngf_reduce_kernel(
    const float* __restrict__ partial, float* __restrict__ out)
{
    double acc = 0.0;
    for (int i = threadIdx.x; i < NBLOCKS; i += blockDim.x)
        acc += (double)partial[i];

    #pragma unroll
    for (int o = 32; o > 0; o >>= 1)
        acc += __shfl_down(acc, o, 64);

    __shared__ double smem[4];
    int lane = threadIdx.x & 63;
    int wid  = threadIdx.x >> 6;
    if (lane == 0) smem[wid] = acc;
    __syncthreads();
    if (threadIdx.x == 0) {
        double s = smem[0] + smem[1] + smem[2] + smem[3];
        out[0] = (float)(s / (double)TOTAL);
    }
}

extern "C" void kernel_launch(void* const* d_in, const int* in_sizes, int n_in,
                              void* d_out, int out_size, void* d_ws, size_t ws_size,
                              hipStream_t stream)
{
    const float* I = (const float*)d_in[0];
    const float* J = (const float*)d_in[1];
    float* out = (float*)d_out;
    float* partial = (float*)d_ws;   // NBLOCKS floats

    ngf_main_kernel<<<NBLOCKS, NT, 0, stream>>>(I, J, partial);
    ngf_reduce_kernel<<<1, 256, 0, stream>>>(partial, out);
}

// Round 19
// 32.384 us; speedup vs baseline: 1.1076x; 1.1076x over previous
//
#include <hip/hip_runtime.h>
#include <stdint.h>

// shape (1,1,192,224,192) f32
#define DD 192
#define HH 224
#define WW 192
#define PLANE (HH*WW)          // 43008
#define TOTAL (DD*HH*WW)       // 8257536

#define HT 4                   // output rows per block (= 4 waves, 1 row each)
#define TROWS 6                // HT+2 halo rows staged
#define DSEG 12                // d-outputs per block (even; 2 per inner iter)
#define NSEG (DD/DSEG)         // 16
#define HTILES (HH/HT)         // 56 (exact)
#define NT 256                 // 4 waves; lane = 3 w-positions (64*3 = 192)
#define NBLOCKS (HTILES*NSEG)  // 896 = 3.5 blocks/CU, all resident (4-block LDS cap)

#define TILEF (TROWS*WW)       // 1152 floats per input per plane-tile
#define PBUF (2*TILEF)         // 2304 floats per plane (I then J)
#define BUFF (2*PBUF)          // 4608 floats per buffer = TWO planes
#define NPIECE 576             // 16B pieces per plane-pair (12 rows x 48)
#define GUARD 4                // head guard so lane0's [3l-1] read is in-bounds

typedef __attribute__((address_space(3))) uint32_t lds_t;
typedef __attribute__((address_space(1))) const uint32_t glb_t;

// Raw barrier + counted vmcnt, PAIR-staged: each stage issues 6 width-16
// loads (2 planes x 3; load 3 of each plane is the 64-piece wave-load
// duplicated by all waves -- benign, proven R16), so outstanding is always
// {pair j, pair j+1} = 12 and WAITV6 retires exactly pair j (FIFO).
// WIDTH-16 ONLY: width-12 global_load_lds corrupts on gfx950.
#define BARRIER() asm volatile("s_barrier" ::: "memory")
#define WAITV6()  asm volatile("s_waitcnt vmcnt(6)" ::: "memory")
#define WAITV0()  asm volatile("s_waitcnt vmcnt(0)" ::: "memory")

struct PP {  // per-plane aggregates for I and J (3 w-outputs each)
    float IPT[3], IPS[3], IHD[3];
    float JPT[3], JPS[3], JHD[3];
};

__global__ __launch_bounds__(NT) void ngf_main_kernel(
    const float* __restrict__ I, const float* __restrict__ J,
    float* __restrict__ partial)
{
    // All combine reads are b32 at (3*lane + c): 3 coprime 32 -> 2 lanes/bank
    // = conflict-free (rows are wave-uniform; row stride 192 = 0 mod 32).
    __shared__ __align__(16) float lds[GUARD + 2 * BUFF + 4];   // 36928 B
    const float EPS2 = 0.04f;  // (2*0.1)^2 — 0.5 Sobel factor folded out

    int t    = threadIdx.x;
    int lane = t & 63;
    int w    = t >> 6;          // wave 0..3 = output h-row
    int bid  = blockIdx.x;
    int th   = bid % HTILES;
    int seg  = bid / HTILES;
    int ds   = seg * DSEG;
    int hb   = th * HT;

    // --- staging pieces (per plane): p = inp*288 + r*48 + c -> LDS float 4p
    //     == inp*TILEF + r*WW + 4c. Loads m=0,1: p = t, t+256. Load m=2:
    //     p = 512+lane for ALL waves (benign duplicate).
    const float* sp[3];
    int lo[3];
    #pragma unroll
    for (int m = 0; m < 3; ++m) {
        int p = (m < 2) ? (t + m * NT) : (512 + lane);
        int inp = (p >= NPIECE / 2) ? 1 : 0;
        int q   = p - inp * (NPIECE / 2);
        int r   = q / 48, c = q % 48;
        int srow = min(max(hb - 1 + r, 0), HH - 1);   // replicate h-halo at load
        sp[m] = (inp ? J : I) + srow * WW + c * 4;
        lo[m] = GUARD + 4 * p;
    }

    auto dcl = [&](int m) { return min(max(ds + m, 0), DD - 1); };

    // stage one PAIR of planes (da, db) into buffer buf (slots 0,1)
    auto stage_pair = [&](int da, int db, int buf) {
        size_t pa = (size_t)da * PLANE;
        size_t pb = (size_t)db * PLANE;
        #pragma unroll
        for (int m = 0; m < 3; ++m)
            __builtin_amdgcn_global_load_lds((glb_t*)(sp[m] + pa),
                (lds_t*)(&lds[buf * BUFF + lo[m]]), 16, 0, 0);
        #pragma unroll
        for (int m = 0; m < 3; ++m)
            __builtin_amdgcn_global_load_lds((glb_t*)(sp[m] + pb),
                (lds_t*)(&lds[buf * BUFF + PBUF + lo[m]]), 16, 0, 0);
    };

    // --- compute mapping: lane covers w-positions 3*lane .. 3*lane+2 ---
    int l3 = 3 * lane;
    bool b0  = (lane == 0);    // true image left boundary
    bool b63 = (lane == 63);   // true image right boundary

    auto combine = [&](int buf, int slot) -> PP {
        PP P;
        #pragma unroll
        for (int j = 0; j < 3; ++j) {
            P.IPT[j] = 0.f; P.IPS[j] = 0.f; P.IHD[j] = 0.f;
            P.JPT[j] = 0.f; P.JPS[j] = 0.f; P.JHD[j] = 0.f;
        }
        const float* base = &lds[GUARD + buf * BUFF + slot * PBUF];
        #pragma unroll
        for (int b = 0; b < 3; ++b) {
            const float* BI = base + (w + b) * WW;   // wave-uniform row
            const float* BJ = BI + TILEF;
            {
                float Lr = BI[l3 - 1];
                float x0 = BI[l3], x1 = BI[l3 + 1], x2 = BI[l3 + 2];
                float Rr = BI[l3 + 3];
                float L = b0  ? x0 : Lr;   // replicate pad at w=0
                float R = b63 ? x2 : Rr;   // replicate pad at w=191
                float s0 = L  + x0 + x1;
                float s1 = x0 + x1 + x2;
                float s2 = x1 + x2 + R;
                P.IPT[0] += x1 - L;
                P.IPT[1] += x2 - x0;
                P.IPT[2] += R  - x1;
                P.IPS[0] += s0; P.IPS[1] += s1; P.IPS[2] += s2;
                if (b == 0) { P.IHD[0] -= s0; P.IHD[1] -= s1; P.IHD[2] -= s2; }
                if (b == 2) { P.IHD[0] += s0; P.IHD[1] += s1; P.IHD[2] += s2; }
            }
            {
                float Lr = BJ[l3 - 1];
                float x0 = BJ[l3], x1 = BJ[l3 + 1], x2 = BJ[l3 + 2];
                float Rr = BJ[l3 + 3];
                float L = b0  ? x0 : Lr;
                float R = b63 ? x2 : Rr;
                float s0 = L  + x0 + x1;
                float s1 = x0 + x1 + x2;
                float s2 = x1 + x2 + R;
                P.JPT[0] += x1 - L;
                P.JPT[1] += x2 - x0;
                P.JPT[2] += R  - x1;
                P.JPS[0] += s0; P.JPS[1] += s1; P.JPS[2] += s2;
                if (b == 0) { P.JHD[0] -= s0; P.JHD[1] -= s1; P.JHD[2] -= s2; }
                if (b == 2) { P.JHD[0] += s0; P.JHD[1] += s1; P.JHD[2] += s2; }
            }
        }
        return P;
    };

    float acc = 0.0f;
    PP p[3];

    // NGF for output k (planes k-1,k,k+1 live in rotation)
    auto ngf = [&](int k) {
        int sa = k % 3, sb2 = (k + 1) % 3, sc = (k + 2) % 3;
        #pragma unroll
        for (int j = 0; j < 3; ++j) {
            float Ix = p[sa].IPT[j] + p[sb2].IPT[j] + p[sc].IPT[j];
            float Iy = p[sa].IHD[j] + p[sb2].IHD[j] + p[sc].IHD[j];
            float Iz = p[sc].IPS[j] - p[sa].IPS[j];
            float Jx = p[sa].JPT[j] + p[sb2].JPT[j] + p[sc].JPT[j];
            float Jy = p[sa].JHD[j] + p[sb2].JHD[j] + p[sc].JHD[j];
            float Jz = p[sc].JPS[j] - p[sa].JPS[j];
            float Imag = fmaf(Ix, Ix, fmaf(Iy, Iy, fmaf(Iz, Iz, EPS2)));
            float Jmag = fmaf(Jx, Jx, fmaf(Jy, Jy, fmaf(Jz, Jz, EPS2)));
            float dot  = fmaf(Ix, Jx, fmaf(Iy, Jy, Iz * Jz));
            acc += 1.0f - (dot * dot) * __builtin_amdgcn_rcpf(Imag * Jmag);
        }
    };

    // --- prologue ---  pair j holds planes (2j-1, 2j); pair j -> buffer j&1
    stage_pair(dcl(-1), dcl(0), 0);   // outstanding: {P0}=6
    stage_pair(dcl(1),  dcl(2), 1);   // {P0,P1}=12
    WAITV6(); BARRIER();              // pair0 landed everywhere
    p[0] = combine(0, 0);             // plane -1
    p[1] = combine(0, 1);             // plane  0
    BARRIER();                        // all waves done reading buf0
    stage_pair(dcl(3), dcl(4), 0);    // pair2 -> buf0; {P1,P2}=12

    // --- main loop: pairs j=1..DSEG/2 (outputs 2j-2, 2j-1) ---
    #pragma unroll
    for (int j = 1; j <= DSEG / 2; ++j) {
        if (j < DSEG / 2) { WAITV6(); }   // retire pair j, keep pair j+1 in flight
        else              { WAITV0(); }   // last pair: drain
        BARRIER();                        // pair j visible to all waves
        int buf = j & 1;
        p[(2 * j) % 3]     = combine(buf, 0);   // plane 2j-1
        ngf(2 * j - 2);
        p[(2 * j + 1) % 3] = combine(buf, 1);   // plane 2j
        ngf(2 * j - 1);
        if (j < DSEG / 2) {
            BARRIER();                    // all waves done reading buf
            if (j + 2 <= DSEG / 2)
                stage_pair(dcl(2 * j + 3), dcl(2 * j + 4), buf);  // pair j+2 -> buf j&1 ✓
        }
    }

    // --- reduction: 4 waves ---
    #pragma unroll
    for (int o = 32; o > 0; o >>= 1)
        acc += __shfl_down(acc, o, 64);

    __shared__ float smem[NT / 64];
    if (lane == 0) smem[w] = acc;
    __syncthreads();
    if (t == 0)
        partial[bid] = smem[0] + smem[1] + smem[2] + smem[3];
}

__global__ __launch_bounds__(256) void ngf_reduce_kernel(
    const float* __restrict__ partial, float* __restrict__ out)
{
    double acc = 0.0;
    for (int i = threadIdx.x; i < NBLOCKS; i += blockDim.x)
        acc += (double)partial[i];

    #pragma unroll
    for (int o = 32; o > 0; o >>= 1)
        acc += __shfl_down(acc, o, 64);

    __shared__ double smem[4];
    int lane = threadIdx.x & 63;
    int wid  = threadIdx.x >> 6;
    if (lane == 0) smem[wid] = acc;
    __syncthreads();
    if (threadIdx.x == 0) {
        double s = smem[0] + smem[1] + smem[2] + smem[3];
        out[0] = (float)(s / (double)TOTAL);
    }
}

extern "C" void kernel_launch(void* const* d_in, const int* in_sizes, int n_in,
                              void* d_out, int out_size, void* d_ws, size_t ws_size,
                              hipStream_t stream)
{
    const float* I = (const float*)d_in[0];
    const float* J = (const float*)d_in[1];
    float* out = (float*)d_out;
    float* partial = (float*)d_ws;   // NBLOCKS floats

    ngf_main_kernel<<<NBLOCKS, NT, 0, stream>>>(I, J, partial);
    ngf_reduce_kernel<<<1, 256, 0, stream>>>(partial, out);
}

// Round 20
// 29.904 us; speedup vs baseline: 1.1994x; 1.0829x over previous
//
#include <hip/hip_runtime.h>
#include <stdint.h>

// shape (1,1,192,224,192) f32
#define DD 192
#define HH 224
#define WW 192
#define PLANE (HH*WW)          // 43008
#define TOTAL (DD*HH*WW)       // 8257536

#define HT 4                   // output rows per block (= 4 waves, 1 row each)
#define TROWS 6                // HT+2 halo rows staged
#define DSEG 6                 // d-outputs per block
#define NSEG (DD/DSEG)         // 32
#define HTILES (HH/HT)         // 56 (exact)
#define NT 256                 // 4 waves; lane = 3 w-positions (64*3 = 192)
#define NBLOCKS (HTILES*NSEG)  // 1792 = 7 blocks/CU; 1792%8==0 -> clean XCD chunks

#define TILEF (TROWS*WW)       // 1152 floats per input per plane-tile
#define BUFF (2*TILEF)         // 2304 floats per buffer (I then J)
#define NPIECE 576             // 16B pieces per plane-pair (12 rows x 48)
#define GUARD 4                // head guard so lane0's [3l-1] read is in-bounds

typedef __attribute__((address_space(3))) uint32_t lds_t;
typedef __attribute__((address_space(1))) const uint32_t glb_t;

// Raw barrier + counted vmcnt. UNIFORM ledger: every wave issues exactly 3
// width-16 loads per stage (load 2 is the same 64-piece wave-load duplicated
// by all 4 waves -- benign same-data LDS writes, proven R16), so WAITV3
// retires exactly the oldest stage for every wave, no branches.
// WIDTH-16 ONLY: width-12 global_load_lds corrupts data on gfx950
// (R8/R13/R14 nonzero absmax; every width-16 round exact).
#define BARRIER() asm volatile("s_barrier" ::: "memory")
#define WAITV3()  asm volatile("s_waitcnt vmcnt(3)" ::: "memory")
#define WAITV0()  asm volatile("s_waitcnt vmcnt(0)" ::: "memory")

struct PP {  // per-plane aggregates for I and J (3 w-outputs each)
    float IPT[3], IPS[3], IHD[3];
    float JPT[3], JPS[3], JHD[3];
};

__global__ __launch_bounds__(NT) void ngf_main_kernel(
    const float* __restrict__ I, const float* __restrict__ J,
    float* __restrict__ partial)
{
    // All combine reads are b32 at (3*lane + c): 3 coprime 32 -> 2 lanes/bank
    // = conflict-free (rows are wave-uniform; row stride 192 = 0 mod 32).
    __shared__ __align__(16) float lds[GUARD + 2 * BUFF + 4];
    const float EPS2 = 0.04f;  // (2*0.1)^2 — 0.5 Sobel factor folded out

    int t    = threadIdx.x;
    int lane = t & 63;
    int w    = t >> 6;          // wave 0..3 = output h-row

    // T1: XCD-aware bijective swizzle (nwg=1792, %8==0). Consecutive logical
    // bids share the same 8 d-planes (one 56-block seg-group reads ~2.75 MB
    // -> fits one XCD L2); chunk them per-XCD instead of round-robin.
    int bid0 = blockIdx.x;
    int bid  = (bid0 & 7) * (NBLOCKS / 8) + (bid0 >> 3);

    int th   = bid % HTILES;
    int seg  = bid / HTILES;
    int ds   = seg * DSEG;
    int hb   = th * HT;

    // --- staging: 576 float4 pieces, piece-contiguous LDS layout.
    //     piece p = inp*288 + r*48 + c  ->  LDS float offset 4p
    //     == inp*TILEF + r*WW + 4c (row-major), so combine addressing holds.
    //     Loads 0,1: p = t, t+256 (uniform). Load 2: p = 512+lane for ALL
    //     waves (4x duplicate of the same data -> benign, uniform vmcnt).
    const float* sp[3];
    int lo[3];
    #pragma unroll
    for (int m = 0; m < 3; ++m) {
        int p = (m < 2) ? (t + m * NT) : (512 + lane);
        int inp = (p >= NPIECE / 2) ? 1 : 0;
        int q   = p - inp * (NPIECE / 2);
        int r   = q / 48, c = q % 48;
        int srow = min(max(hb - 1 + r, 0), HH - 1);   // replicate h-halo at load
        sp[m] = (inp ? J : I) + srow * WW + c * 4;
        lo[m] = GUARD + 4 * p;
    }

    auto stage = [&](int dp, int buf) {
        size_t poff = (size_t)dp * PLANE;
        #pragma unroll
        for (int m = 0; m < 3; ++m) {
            __builtin_amdgcn_global_load_lds((glb_t*)(sp[m] + poff),
                (lds_t*)(&lds[buf * BUFF + lo[m]]), 16, 0, 0);
        }
    };

    // --- compute mapping: lane covers w-positions 3*lane .. 3*lane+2 ---
    int l3 = 3 * lane;
    bool b0  = (lane == 0);    // true image left boundary
    bool b63 = (lane == 63);   // true image right boundary

    auto combine = [&](int buf) -> PP {
        PP P;
        #pragma unroll
        for (int j = 0; j < 3; ++j) {
            P.IPT[j] = 0.f; P.IPS[j] = 0.f; P.IHD[j] = 0.f;
            P.JPT[j] = 0.f; P.JPS[j] = 0.f; P.JHD[j] = 0.f;
        }
        const float* base = &lds[GUARD + buf * BUFF];
        #pragma unroll
        for (int b = 0; b < 3; ++b) {
            const float* BI = base + (w + b) * WW;   // wave-uniform row
            const float* BJ = BI + TILEF;
            {
                float Lr = BI[l3 - 1];
                float x0 = BI[l3], x1 = BI[l3 + 1], x2 = BI[l3 + 2];
                float Rr = BI[l3 + 3];
                float L = b0  ? x0 : Lr;   // replicate pad at w=0
                float R = b63 ? x2 : Rr;   // replicate pad at w=191
                float s0 = L  + x0 + x1;
                float s1 = x0 + x1 + x2;
                float s2 = x1 + x2 + R;
                P.IPT[0] += x1 - L;
                P.IPT[1] += x2 - x0;
                P.IPT[2] += R  - x1;
                P.IPS[0] += s0; P.IPS[1] += s1; P.IPS[2] += s2;
                if (b == 0) { P.IHD[0] -= s0; P.IHD[1] -= s1; P.IHD[2] -= s2; }
                if (b == 2) { P.IHD[0] += s0; P.IHD[1] += s1; P.IHD[2] += s2; }
            }
            {
                float Lr = BJ[l3 - 1];
                float x0 = BJ[l3], x1 = BJ[l3 + 1], x2 = BJ[l3 + 2];
                float Rr = BJ[l3 + 3];
                float L = b0  ? x0 : Lr;
                float R = b63 ? x2 : Rr;
                float s0 = L  + x0 + x1;
                float s1 = x0 + x1 + x2;
                float s2 = x1 + x2 + R;
                P.JPT[0] += x1 - L;
                P.JPT[1] += x2 - x0;
                P.JPT[2] += R  - x1;
                P.JPS[0] += s0; P.JPS[1] += s1; P.JPS[2] += s2;
                if (b == 0) { P.JHD[0] -= s0; P.JHD[1] -= s1; P.JHD[2] -= s2; }
                if (b == 2) { P.JHD[0] += s0; P.JHD[1] += s1; P.JHD[2] += s2; }
            }
        }
        return P;
    };

    auto dcl = [&](int m) { return min(max(ds + m, 0), DD - 1); };

    // --- prologue ---
    // plane m -> buffer (m+1)&1 :  -1->0, 0->1, 1->0, 2->1
    PP p[3];
    stage(dcl(-1), 0);           // outstanding: {S-1}
    stage(dcl(0), 1);            // {S-1, S0}
    WAITV3(); BARRIER();         // plane -1 landed everywhere
    p[0] = combine(0);
    BARRIER();                   // all waves done reading buf0
    stage(dcl(1), 0);            // {S0, S1}
    WAITV3(); BARRIER();         // plane 0 landed
    p[1] = combine(1);
    BARRIER();                   // done reading buf1
    stage(dcl(2), 1);            // {S1, S2}

    float acc = 0.0f;
    #pragma unroll
    for (int k = 0; k < DSEG; ++k) {
        int buf = k & 1;                 // plane k+1 sits in buffer (k+2)&1 = k&1
        if (k < DSEG - 1) { WAITV3(); }  // retire S(k+1), keep S(k+2) in flight
        else             { WAITV0(); }   // last: drain
        BARRIER();                       // plane k+1 visible to all waves

        // T5: favor compute-phase waves on the CU scheduler (blocks on a CU
        // run phase-skewed, so staging waves can yield to VALU-burst waves).
        __builtin_amdgcn_s_setprio(1);
        int sa = k % 3, sb2 = (k + 1) % 3, sc = (k + 2) % 3;
        p[sc] = combine(buf);

        #pragma unroll
        for (int j = 0; j < 3; ++j) {
            float Ix = p[sa].IPT[j] + p[sb2].IPT[j] + p[sc].IPT[j];
            float Iy = p[sa].IHD[j] + p[sb2].IHD[j] + p[sc].IHD[j];
            float Iz = p[sc].IPS[j] - p[sa].IPS[j];
            float Jx = p[sa].JPT[j] + p[sb2].JPT[j] + p[sc].JPT[j];
            float Jy = p[sa].JHD[j] + p[sb2].JHD[j] + p[sc].JHD[j];
            float Jz = p[sc].JPS[j] - p[sa].JPS[j];

            float Imag = fmaf(Ix, Ix, fmaf(Iy, Iy, fmaf(Iz, Iz, EPS2)));
            float Jmag = fmaf(Jx, Jx, fmaf(Jy, Jy, fmaf(Jz, Jz, EPS2)));
            float dot  = fmaf(Ix, Jx, fmaf(Iy, Jy, Iz * Jz));
            acc += 1.0f - (dot * dot) * __builtin_amdgcn_rcpf(Imag * Jmag);
        }
        __builtin_amdgcn_s_setprio(0);

        if (k < DSEG - 1) {
            BARRIER();                   // all waves done reading buf
            if (k <= DSEG - 3)
                stage(dcl(k + 3), buf);  // plane k+3 -> buffer (k+4)&1 = k&1 ✓
        }
    }

    // --- reduction: 4 waves ---
    #pragma unroll
    for (int o = 32; o > 0; o >>= 1)
        acc += __shfl_down(acc, o, 64);

    __shared__ float smem[NT / 64];
    if (lane == 0) smem[w] = acc;
    __syncthreads();
    if (t == 0)
        partial[bid] = smem[0] + smem[1] + smem[2] + smem[3];
}

__global__ __launch_bounds__(256) void ngf_reduce_kernel(
    const float* __restrict__ partial, float* __restrict__ out)
{
    double acc = 0.0;
    for (int i = threadIdx.x; i < NBLOCKS; i += blockDim.x)
        acc += (double)partial[i];

    #pragma unroll
    for (int o = 32; o > 0; o >>= 1)
        acc += __shfl_down(acc, o, 64);

    __shared__ double smem[4];
    int lane = threadIdx.x & 63;
    int wid  = threadIdx.x >> 6;
    if (lane == 0) smem[wid] = acc;
    __syncthreads();
    if (threadIdx.x == 0) {
        double s = smem[0] + smem[1] + smem[2] + smem[3];
        out[0] = (float)(s / (double)TOTAL);
    }
}

extern "C" void kernel_launch(void* const* d_in, const int* in_sizes, int n_in,
                              void* d_out, int out_size, void* d_ws, size_t ws_size,
                              hipStream_t stream)
{
    const float* I = (const float*)d_in[0];
    const float* J = (const float*)d_in[1];
    float* out = (float*)d_out;
    float* partial = (float*)d_ws;   // NBLOCKS floats

    ngf_main_kernel<<<NBLOCKS, NT, 0, stream>>>(I, J, partial);
    ngf_reduce_kernel<<<1, 256, 0, stream>>>(partial, out);
}